// Round 1
// baseline (516.332 us; speedup 1.0000x reference)
//
#include <hip/hip_runtime.h>
#include <math.h>
#include <stdint.h>

// MFMA fragment types (guide §3, compile-verified on gfx950)
typedef __attribute__((ext_vector_type(8))) short bf16x8;   // 8 bf16 in 4 VGPRs
typedef __attribute__((ext_vector_type(4))) float f32x4;    // 4 fp32 acc

__device__ __forceinline__ unsigned short f2bf(float f) {
    union { float f; unsigned u; } v; v.f = f;
    return (unsigned short)((v.u + 0x7fffu + ((v.u >> 16) & 1u)) >> 16); // RNE
}

// ---------------- fp32 -> bf16 elementwise (x4 vectorized) ----------------
__global__ void k_convert(const float* __restrict__ in, unsigned short* __restrict__ out, int n4) {
    int i = blockIdx.x * blockDim.x + threadIdx.x;
    if (i >= n4) return;
    float4 f = ((const float4*)in)[i];
    ushort4 o;
    o.x = f2bf(f.x); o.y = f2bf(f.y); o.z = f2bf(f.z); o.w = f2bf(f.w);
    ((ushort4*)out)[i] = o;
}

// ---------------- fp32 [R][C] -> bf16 [C][R] (tiled transpose) ----------------
__global__ void k_transpose(const float* __restrict__ in, unsigned short* __restrict__ out, int R, int C) {
    __shared__ float tile[32][33];
    int c0 = blockIdx.x * 32, r0 = blockIdx.y * 32;
    int tx = threadIdx.x, ty = threadIdx.y; // block (32,8)
#pragma unroll
    for (int i = 0; i < 4; ++i)
        tile[ty + i * 8][tx] = in[(size_t)(r0 + ty + i * 8) * C + c0 + tx];
    __syncthreads();
#pragma unroll
    for (int i = 0; i < 4; ++i)
        out[(size_t)(c0 + ty + i * 8) * R + r0 + tx] = f2bf(tile[tx][ty + i * 8]);
}

// ---------------- 128x128 bf16 MFMA GEMM core ----------------
// A [M][K] bf16 row-major, Bt [N][K] bf16 row-major (i.e. B^T). K % 32 == 0,
// M % 128 == 0, N % 128 == 0. Block = 256 threads = 4 waves, each wave 64x64.
// LDS rows padded to 40 shorts (80 B = 20 banks -> 2-way conflicts only, free).
#define LDT 40

__device__ __forceinline__ void gemm_core(
    const unsigned short* __restrict__ A, const unsigned short* __restrict__ Bt,
    int K, unsigned short* As, unsigned short* Bs, f32x4 (&acc)[4][4])
{
    const int tid  = threadIdx.x;
    const int lane = tid & 63;
    const int w    = tid >> 6;
    const int wm   = (w >> 1) * 64, wn = (w & 1) * 64;
    const int l15  = lane & 15, quad = lane >> 4;
    const int m0 = blockIdx.x * 128, n0 = blockIdx.y * 128;

    const f32x4 zero = {0.f, 0.f, 0.f, 0.f};
#pragma unroll
    for (int i = 0; i < 4; ++i)
#pragma unroll
        for (int j = 0; j < 4; ++j) acc[i][j] = zero;

    // staging: 128 rows x 64B per tile; thread handles rows r0 and r0+64, 16B each
    const int r0 = tid >> 2, p8 = (tid & 3) * 8;
    const unsigned short* Ag0 = A  + (size_t)(m0 + r0) * K + p8;
    const unsigned short* Ag1 = A  + (size_t)(m0 + r0 + 64) * K + p8;
    const unsigned short* Bg0 = Bt + (size_t)(n0 + r0) * K + p8;
    const unsigned short* Bg1 = Bt + (size_t)(n0 + r0 + 64) * K + p8;

    int4 a0 = *(const int4*)Ag0;
    int4 a1 = *(const int4*)Ag1;
    int4 b0 = *(const int4*)Bg0;
    int4 b1 = *(const int4*)Bg1;

    const int nk = K >> 5;
    for (int kt = 0; kt < nk; ++kt) {
        __syncthreads();
        *(int4*)&As[r0 * LDT + p8]        = a0;
        *(int4*)&As[(r0 + 64) * LDT + p8] = a1;
        *(int4*)&Bs[r0 * LDT + p8]        = b0;
        *(int4*)&Bs[(r0 + 64) * LDT + p8] = b1;
        __syncthreads();
        if (kt + 1 < nk) {  // prefetch next K-slab into regs, overlaps MFMA
            int koff = (kt + 1) * 32;
            a0 = *(const int4*)(Ag0 + koff);
            a1 = *(const int4*)(Ag1 + koff);
            b0 = *(const int4*)(Bg0 + koff);
            b1 = *(const int4*)(Bg1 + koff);
        }
        bf16x8 af[4], bfr[4];
#pragma unroll
        for (int mi = 0; mi < 4; ++mi)
            af[mi] = *(const bf16x8*)&As[(wm + mi * 16 + l15) * LDT + quad * 8];
#pragma unroll
        for (int nj = 0; nj < 4; ++nj)
            bfr[nj] = *(const bf16x8*)&Bs[(wn + nj * 16 + l15) * LDT + quad * 8];
#pragma unroll
        for (int mi = 0; mi < 4; ++mi)
#pragma unroll
            for (int nj = 0; nj < 4; ++nj)
                acc[mi][nj] = __builtin_amdgcn_mfma_f32_16x16x32_bf16(af[mi], bfr[nj], acc[mi][nj], 0, 0, 0);
    }
}

// QKV GEMM: A = x bf16 [8192][768], Bt = WqkvT [2304][768].
// Epilogue scatters into Q,K [24][4096][64] and Vt [24][64][4096] (all bf16).
__global__ __launch_bounds__(256) void k_gemm_qkv(
    const unsigned short* __restrict__ A, const unsigned short* __restrict__ Bt,
    const float* __restrict__ bias,
    unsigned short* __restrict__ Qo, unsigned short* __restrict__ Ko,
    unsigned short* __restrict__ Vt)
{
    __shared__ __align__(16) unsigned short As[128 * LDT];
    __shared__ __align__(16) unsigned short Bs[128 * LDT];
    f32x4 acc[4][4];
    gemm_core(A, Bt, 768, As, Bs, acc);

    const int tid = threadIdx.x, lane = tid & 63, w = tid >> 6;
    const int wm = (w >> 1) * 64, wn = (w & 1) * 64;
    const int l15 = lane & 15, quad = lane >> 4;
    const int m0 = blockIdx.x * 128, n0 = blockIdx.y * 128;
#pragma unroll
    for (int nj = 0; nj < 4; ++nj) {
        int cg = n0 + wn + nj * 16 + l15;        // column in [0,2304)
        float bv = bias[cg];
        int which = cg / 768;                    // 0=q 1=k 2=v
        int rem = cg - which * 768;
        int h = rem >> 6, d = rem & 63;
#pragma unroll
        for (int mi = 0; mi < 4; ++mi) {
#pragma unroll
            for (int r = 0; r < 4; ++r) {
                int rg = m0 + wm + mi * 16 + quad * 4 + r;   // row in [0,8192)
                int b = rg >> 12, t = rg & 4095;
                int bh = b * 12 + h;
                unsigned short ob = f2bf(acc[mi][nj][r] + bv);
                if (which == 2)
                    Vt[((size_t)bh * 64 + d) * 4096 + t] = ob;
                else {
                    unsigned short* dst = (which == 0) ? Qo : Ko;
                    dst[((size_t)bh * 4096 + t) * 64 + d] = ob;
                }
            }
        }
    }
}

// Proj GEMM: A = y bf16 [8192][768], Bt = WprojT [768][768], out fp32 + bias
__global__ __launch_bounds__(256) void k_gemm_proj(
    const unsigned short* __restrict__ A, const unsigned short* __restrict__ Bt,
    const float* __restrict__ bias, float* __restrict__ out)
{
    __shared__ __align__(16) unsigned short As[128 * LDT];
    __shared__ __align__(16) unsigned short Bs[128 * LDT];
    f32x4 acc[4][4];
    gemm_core(A, Bt, 768, As, Bs, acc);

    const int tid = threadIdx.x, lane = tid & 63, w = tid >> 6;
    const int wm = (w >> 1) * 64, wn = (w & 1) * 64;
    const int l15 = lane & 15, quad = lane >> 4;
    const int m0 = blockIdx.x * 128, n0 = blockIdx.y * 128;
#pragma unroll
    for (int nj = 0; nj < 4; ++nj) {
        int cg = n0 + wn + nj * 16 + l15;
        float bv = bias[cg];
#pragma unroll
        for (int mi = 0; mi < 4; ++mi)
#pragma unroll
            for (int r = 0; r < 4; ++r) {
                int rg = m0 + wm + mi * 16 + quad * 4 + r;
                out[(size_t)rg * 768 + cg] = acc[mi][nj][r] + bv;
            }
    }
}

// ---------------- Flash attention, causal ----------------
// grid (T/64, BH=24), block 256 (4 waves). Wave w owns q rows qt*64+w*16..+16.
// Key tiles of 64; kt in [0, qt] -> uniform trip count, barriers legal.
#define LDK 72   // 64 + 8 pad shorts: 144B row stride -> 2-way conflicts only

__global__ __launch_bounds__(256) void k_attn(
    const unsigned short* __restrict__ Q, const unsigned short* __restrict__ K,
    const unsigned short* __restrict__ Vt, unsigned short* __restrict__ Y)
{
    __shared__ __align__(16) unsigned short Ks[64 * LDK];
    __shared__ __align__(16) unsigned short Vs[64 * LDK];
    __shared__ __align__(16) unsigned short Ps[64 * LDK];   // 4 waves x 16 rows

    const int tid = threadIdx.x, lane = tid & 63, w = tid >> 6;
    const int l15 = lane & 15, quad = lane >> 4;
    const int qt = blockIdx.x, bh = blockIdx.y;
    const int b = bh / 12, h = bh % 12;
    const size_t qkbase = (size_t)bh * 4096 * 64;   // [bh][t][d]
    const size_t vbase  = (size_t)bh * 64 * 4096;   // [bh][d][t]

    // Q A-fragments for this wave's 16 rows (held in regs whole kernel)
    const int qrow_a = qt * 64 + w * 16 + l15;
    bf16x8 qf0 = *(const bf16x8*)(Q + qkbase + (size_t)qrow_a * 64 + quad * 8);
    bf16x8 qf1 = *(const bf16x8*)(Q + qkbase + (size_t)qrow_a * 64 + 32 + quad * 8);

    const f32x4 zero = {0.f, 0.f, 0.f, 0.f};
    f32x4 O[4];
#pragma unroll
    for (int dj = 0; dj < 4; ++dj) O[dj] = zero;
    float mrow[4], lrow[4];
#pragma unroll
    for (int r = 0; r < 4; ++r) { mrow[r] = -INFINITY; lrow[r] = 0.f; }
    const float cscale = 0.18033688011f;  // (1/sqrt(64)) * log2(e); softmax in exp2 domain

    const int sr = tid >> 3, sp = (tid & 7) * 8;  // staging: rows sr, sr+32; 16B chunks
    const int qrow_c = qt * 64 + w * 16 + quad * 4;

    for (int kt = 0; kt <= qt; ++kt) {
        __syncthreads();
        {   // stage K tile [64 keys][64 d] and Vt tile [64 d][64 keys]
            int4 k0 = *(const int4*)(K  + qkbase + (size_t)(kt * 64 + sr) * 64 + sp);
            int4 k1 = *(const int4*)(K  + qkbase + (size_t)(kt * 64 + sr + 32) * 64 + sp);
            int4 v0 = *(const int4*)(Vt + vbase + (size_t)sr * 4096 + kt * 64 + sp);
            int4 v1 = *(const int4*)(Vt + vbase + (size_t)(sr + 32) * 4096 + kt * 64 + sp);
            *(int4*)&Ks[sr * LDK + sp]        = k0;
            *(int4*)&Ks[(sr + 32) * LDK + sp] = k1;
            *(int4*)&Vs[sr * LDK + sp]        = v0;
            *(int4*)&Vs[(sr + 32) * LDK + sp] = v1;
        }
        __syncthreads();

        // S = Q K^T  (16 x 64 per wave)
        f32x4 s[4];
#pragma unroll
        for (int nj = 0; nj < 4; ++nj) {
            bf16x8 kf0 = *(const bf16x8*)&Ks[(nj * 16 + l15) * LDK + quad * 8];
            bf16x8 kf1 = *(const bf16x8*)&Ks[(nj * 16 + l15) * LDK + 32 + quad * 8];
            f32x4 z = zero;
            z = __builtin_amdgcn_mfma_f32_16x16x32_bf16(qf0, kf0, z, 0, 0, 0);
            z = __builtin_amdgcn_mfma_f32_16x16x32_bf16(qf1, kf1, z, 0, 0, 0);
            s[nj] = z;
        }

        // scale + causal mask (only diagonal tile needs masking)
        const bool diag = (kt == qt);
#pragma unroll
        for (int nj = 0; nj < 4; ++nj)
#pragma unroll
            for (int r = 0; r < 4; ++r) {
                float sv = s[nj][r] * cscale;
                if (diag && (kt * 64 + nj * 16 + l15 > qrow_c + r)) sv = -INFINITY;
                s[nj][r] = sv;
            }

        // online softmax: row max across 64 cols (16 lanes of quad x 4 frags)
        float rm[4];
#pragma unroll
        for (int r = 0; r < 4; ++r) {
            float v = fmaxf(fmaxf(s[0][r], s[1][r]), fmaxf(s[2][r], s[3][r]));
            v = fmaxf(v, __shfl_xor(v, 1));
            v = fmaxf(v, __shfl_xor(v, 2));
            v = fmaxf(v, __shfl_xor(v, 4));
            v = fmaxf(v, __shfl_xor(v, 8));
            rm[r] = v;
        }
        float alpha[4];
#pragma unroll
        for (int r = 0; r < 4; ++r) {
            float mnew = fmaxf(mrow[r], rm[r]);   // finite from kt=0 (key 0 visible)
            alpha[r] = exp2f(mrow[r] - mnew);
            mrow[r] = mnew;
        }
        float prs[4] = {0.f, 0.f, 0.f, 0.f};
#pragma unroll
        for (int nj = 0; nj < 4; ++nj)
#pragma unroll
            for (int r = 0; r < 4; ++r) {
                float p = exp2f(s[nj][r] - mrow[r]);
                s[nj][r] = p;
                prs[r] += p;
            }
#pragma unroll
        for (int r = 0; r < 4; ++r) {
            float v = prs[r];
            v += __shfl_xor(v, 1);
            v += __shfl_xor(v, 2);
            v += __shfl_xor(v, 4);
            v += __shfl_xor(v, 8);
            lrow[r] = lrow[r] * alpha[r] + v;
        }
#pragma unroll
        for (int dj = 0; dj < 4; ++dj)
#pragma unroll
            for (int r = 0; r < 4; ++r) O[dj][r] *= alpha[r];

        // P: C-layout -> A-layout via LDS (wave-private 16x64 region)
#pragma unroll
        for (int nj = 0; nj < 4; ++nj)
#pragma unroll
            for (int r = 0; r < 4; ++r)
                Ps[(w * 16 + quad * 4 + r) * LDK + nj * 16 + l15] = f2bf(s[nj][r]);
        __syncthreads();   // uniform; also guards cross-lane P visibility
        bf16x8 pa0 = *(const bf16x8*)&Ps[(w * 16 + l15) * LDK + quad * 8];
        bf16x8 pa1 = *(const bf16x8*)&Ps[(w * 16 + l15) * LDK + 32 + quad * 8];

        // O += P V   (B-frag from Vt tile: B[k=key][n=d] = Vt[d][key])
#pragma unroll
        for (int dj = 0; dj < 4; ++dj) {
            bf16x8 vf0 = *(const bf16x8*)&Vs[(dj * 16 + l15) * LDK + quad * 8];
            bf16x8 vf1 = *(const bf16x8*)&Vs[(dj * 16 + l15) * LDK + 32 + quad * 8];
            O[dj] = __builtin_amdgcn_mfma_f32_16x16x32_bf16(pa0, vf0, O[dj], 0, 0, 0);
            O[dj] = __builtin_amdgcn_mfma_f32_16x16x32_bf16(pa1, vf1, O[dj], 0, 0, 0);
        }
    }

    // epilogue: O / l  -> Y [b][t][h*64+d] bf16 (A-input of proj GEMM)
#pragma unroll
    for (int r = 0; r < 4; ++r) {
        float inv = 1.0f / lrow[r];
        int t = qt * 64 + w * 16 + quad * 4 + r;
        size_t base = ((size_t)(b * 4096 + t)) * 768 + h * 64;
#pragma unroll
        for (int dj = 0; dj < 4; ++dj)
            Y[base + dj * 16 + l15] = f2bf(O[dj][r] * inv);
    }
}

// ---------------- launch ----------------
extern "C" void kernel_launch(void* const* d_in, const int* in_sizes, int n_in,
                              void* d_out, int out_size, void* d_ws, size_t ws_size,
                              hipStream_t stream) {
    (void)in_sizes; (void)n_in; (void)out_size; (void)ws_size;
    const float* x     = (const float*)d_in[0];
    const float* Wqkv  = (const float*)d_in[1];
    const float* bqkv  = (const float*)d_in[2];
    const float* Wproj = (const float*)d_in[3];
    const float* bproj = (const float*)d_in[4];
    float* out = (float*)d_out;

    char* ws = (char*)d_ws;
    size_t off = 0;
    auto alloc = [&](size_t bytes) -> void* {
        void* p = ws + off;
        off += (bytes + 255) & ~(size_t)255;
        return p;
    };
    unsigned short* xb     = (unsigned short*)alloc((size_t)8192 * 768 * 2);
    unsigned short* WqkvT  = (unsigned short*)alloc((size_t)2304 * 768 * 2);
    unsigned short* WprojT = (unsigned short*)alloc((size_t)768 * 768 * 2);
    unsigned short* Qb     = (unsigned short*)alloc((size_t)24 * 4096 * 64 * 2);
    unsigned short* Kb     = (unsigned short*)alloc((size_t)24 * 4096 * 64 * 2);
    unsigned short* Vtb    = (unsigned short*)alloc((size_t)24 * 64 * 4096 * 2);
    unsigned short* Yb     = (unsigned short*)alloc((size_t)8192 * 768 * 2);

    k_convert<<<6144, 256, 0, stream>>>(x, xb, 8192 * 768 / 4);
    dim3 tb(32, 8);
    k_transpose<<<dim3(72, 24), tb, 0, stream>>>(Wqkv, WqkvT, 768, 2304);
    k_transpose<<<dim3(24, 24), tb, 0, stream>>>(Wproj, WprojT, 768, 768);
    k_gemm_qkv<<<dim3(64, 18), 256, 0, stream>>>(xb, WqkvT, bqkv, Qb, Kb, Vtb);
    k_attn<<<dim3(64, 24), 256, 0, stream>>>(Qb, Kb, Vtb, Yb);
    k_gemm_proj<<<dim3(64, 6), 256, 0, stream>>>(Yb, WprojT, bproj, out);
}

// Round 2
// 464.441 us; speedup vs baseline: 1.1117x; 1.1117x over previous
//
#include <hip/hip_runtime.h>
#include <math.h>
#include <stdint.h>

// MFMA fragment types (guide §3, compile-verified on gfx950)
typedef __attribute__((ext_vector_type(8))) short bf16x8;   // 8 bf16 in 4 VGPRs
typedef __attribute__((ext_vector_type(4))) float f32x4;    // 4 fp32 acc

__device__ __forceinline__ unsigned short f2bf(float f) {
    union { float f; unsigned u; } v; v.f = f;
    return (unsigned short)((v.u + 0x7fffu + ((v.u >> 16) & 1u)) >> 16); // RNE
}

// ---------------- fp32 -> bf16 elementwise (x4 vectorized) ----------------
__global__ void k_convert(const float* __restrict__ in, unsigned short* __restrict__ out, int n4) {
    int i = blockIdx.x * blockDim.x + threadIdx.x;
    if (i >= n4) return;
    float4 f = ((const float4*)in)[i];
    ushort4 o;
    o.x = f2bf(f.x); o.y = f2bf(f.y); o.z = f2bf(f.z); o.w = f2bf(f.w);
    ((ushort4*)out)[i] = o;
}

// ---------------- fp32 [R][C] -> bf16 [C][R] (tiled transpose) ----------------
__global__ void k_transpose(const float* __restrict__ in, unsigned short* __restrict__ out, int R, int C) {
    __shared__ float tile[32][33];
    int c0 = blockIdx.x * 32, r0 = blockIdx.y * 32;
    int tx = threadIdx.x, ty = threadIdx.y; // block (32,8)
#pragma unroll
    for (int i = 0; i < 4; ++i)
        tile[ty + i * 8][tx] = in[(size_t)(r0 + ty + i * 8) * C + c0 + tx];
    __syncthreads();
#pragma unroll
    for (int i = 0; i < 4; ++i)
        out[(size_t)(c0 + ty + i * 8) * R + r0 + tx] = f2bf(tile[tx][ty + i * 8]);
}

// ---------------- 128x128 bf16 MFMA GEMM core ----------------
#define LDT 40

__device__ __forceinline__ void gemm_core(
    const unsigned short* __restrict__ A, const unsigned short* __restrict__ Bt,
    int K, unsigned short* As, unsigned short* Bs, f32x4 (&acc)[4][4])
{
    const int tid  = threadIdx.x;
    const int lane = tid & 63;
    const int w    = tid >> 6;
    const int wm   = (w >> 1) * 64, wn = (w & 1) * 64;
    const int l15  = lane & 15, quad = lane >> 4;
    const int m0 = blockIdx.x * 128, n0 = blockIdx.y * 128;

    const f32x4 zero = {0.f, 0.f, 0.f, 0.f};
#pragma unroll
    for (int i = 0; i < 4; ++i)
#pragma unroll
        for (int j = 0; j < 4; ++j) acc[i][j] = zero;

    const int r0 = tid >> 2, p8 = (tid & 3) * 8;
    const unsigned short* Ag0 = A  + (size_t)(m0 + r0) * K + p8;
    const unsigned short* Ag1 = A  + (size_t)(m0 + r0 + 64) * K + p8;
    const unsigned short* Bg0 = Bt + (size_t)(n0 + r0) * K + p8;
    const unsigned short* Bg1 = Bt + (size_t)(n0 + r0 + 64) * K + p8;

    int4 a0 = *(const int4*)Ag0;
    int4 a1 = *(const int4*)Ag1;
    int4 b0 = *(const int4*)Bg0;
    int4 b1 = *(const int4*)Bg1;

    const int nk = K >> 5;
    for (int kt = 0; kt < nk; ++kt) {
        __syncthreads();
        *(int4*)&As[r0 * LDT + p8]        = a0;
        *(int4*)&As[(r0 + 64) * LDT + p8] = a1;
        *(int4*)&Bs[r0 * LDT + p8]        = b0;
        *(int4*)&Bs[(r0 + 64) * LDT + p8] = b1;
        __syncthreads();
        if (kt + 1 < nk) {
            int koff = (kt + 1) * 32;
            a0 = *(const int4*)(Ag0 + koff);
            a1 = *(const int4*)(Ag1 + koff);
            b0 = *(const int4*)(Bg0 + koff);
            b1 = *(const int4*)(Bg1 + koff);
        }
        bf16x8 af[4], bfr[4];
#pragma unroll
        for (int mi = 0; mi < 4; ++mi)
            af[mi] = *(const bf16x8*)&As[(wm + mi * 16 + l15) * LDT + quad * 8];
#pragma unroll
        for (int nj = 0; nj < 4; ++nj)
            bfr[nj] = *(const bf16x8*)&Bs[(wn + nj * 16 + l15) * LDT + quad * 8];
#pragma unroll
        for (int mi = 0; mi < 4; ++mi)
#pragma unroll
            for (int nj = 0; nj < 4; ++nj)
                acc[mi][nj] = __builtin_amdgcn_mfma_f32_16x16x32_bf16(af[mi], bfr[nj], acc[mi][nj], 0, 0, 0);
    }
}

// QKV GEMM epilogue scatters into Q,K [24][4096][64] and Vt [24][64][4096].
// Q is pre-scaled by (1/sqrt(64))*log2(e) so attention softmax runs in the
// exp2 domain with no per-element scaling.
__global__ __launch_bounds__(256) void k_gemm_qkv(
    const unsigned short* __restrict__ A, const unsigned short* __restrict__ Bt,
    const float* __restrict__ bias,
    unsigned short* __restrict__ Qo, unsigned short* __restrict__ Ko,
    unsigned short* __restrict__ Vt)
{
    __shared__ __align__(16) unsigned short As[128 * LDT];
    __shared__ __align__(16) unsigned short Bs[128 * LDT];
    f32x4 acc[4][4];
    gemm_core(A, Bt, 768, As, Bs, acc);

    const int tid = threadIdx.x, lane = tid & 63, w = tid >> 6;
    const int wm = (w >> 1) * 64, wn = (w & 1) * 64;
    const int l15 = lane & 15, quad = lane >> 4;
    const int m0 = blockIdx.x * 128, n0 = blockIdx.y * 128;
    const float cscale = 0.18033688011f;  // (1/8) * log2(e)
#pragma unroll
    for (int nj = 0; nj < 4; ++nj) {
        int cg = n0 + wn + nj * 16 + l15;        // column in [0,2304)
        float bv = bias[cg];
        int which = cg / 768;                    // 0=q 1=k 2=v
        int rem = cg - which * 768;
        int h = rem >> 6, d = rem & 63;
        float sc = (which == 0) ? cscale : 1.0f;
#pragma unroll
        for (int mi = 0; mi < 4; ++mi) {
#pragma unroll
            for (int r = 0; r < 4; ++r) {
                int rg = m0 + wm + mi * 16 + quad * 4 + r;   // row in [0,8192)
                int b = rg >> 12, t = rg & 4095;
                int bh = b * 12 + h;
                unsigned short ob = f2bf((acc[mi][nj][r] + bv) * sc);
                if (which == 2)
                    Vt[((size_t)bh * 64 + d) * 4096 + t] = ob;
                else {
                    unsigned short* dst = (which == 0) ? Qo : Ko;
                    dst[((size_t)bh * 4096 + t) * 64 + d] = ob;
                }
            }
        }
    }
}

// Proj GEMM: A = y bf16 [8192][768], Bt = WprojT [768][768], out fp32 + bias
__global__ __launch_bounds__(256) void k_gemm_proj(
    const unsigned short* __restrict__ A, const unsigned short* __restrict__ Bt,
    const float* __restrict__ bias, float* __restrict__ out)
{
    __shared__ __align__(16) unsigned short As[128 * LDT];
    __shared__ __align__(16) unsigned short Bs[128 * LDT];
    f32x4 acc[4][4];
    gemm_core(A, Bt, 768, As, Bs, acc);

    const int tid = threadIdx.x, lane = tid & 63, w = tid >> 6;
    const int wm = (w >> 1) * 64, wn = (w & 1) * 64;
    const int l15 = lane & 15, quad = lane >> 4;
    const int m0 = blockIdx.x * 128, n0 = blockIdx.y * 128;
#pragma unroll
    for (int nj = 0; nj < 4; ++nj) {
        int cg = n0 + wn + nj * 16 + l15;
        float bv = bias[cg];
#pragma unroll
        for (int mi = 0; mi < 4; ++mi)
#pragma unroll
            for (int r = 0; r < 4; ++r) {
                int rg = m0 + wm + mi * 16 + quad * 4 + r;
                out[(size_t)rg * 768 + cg] = acc[mi][nj][r] + bv;
            }
    }
}

// ---------------- Flash attention, causal, BARRIER-FREE ----------------
// Each wave independently owns 32 q-rows (2 MFMA row-blocks). K and Vt
// fragments are loaded directly from global in MFMA B-layout (contiguous
// 16B per lane, L2-resident). Only LDS use: wave-private P C->A transform
// (same-wave RAW, no __syncthreads anywhere).
// Block 256 = 4 waves; wave w of block bx handles qi = (31-bx)+32w so each
// block mixes short/long waves and longest blocks launch first.
#define LDP 68   // P row stride in shorts: quad stride 544B = 8 banks -> conflict-free

__global__ __launch_bounds__(256, 2) void k_attn(
    const unsigned short* __restrict__ Q, const unsigned short* __restrict__ K,
    const unsigned short* __restrict__ Vt, unsigned short* __restrict__ Y)
{
    __shared__ __align__(16) unsigned short Ps[4 * 32 * LDP];

    const int tid = threadIdx.x, lane = tid & 63, w = tid >> 6;
    const int l15 = lane & 15, quad = lane >> 4;
    const int qi = (31 - (int)blockIdx.x) + 32 * w;   // 0..127, long first
    const int bh = blockIdx.y;
    const size_t qkbase = (size_t)bh * 4096 * 64;     // [bh][t][d]
    const size_t vbase  = (size_t)bh * 64 * 4096;     // [bh][d][t]
    const int q0 = qi * 32;
    unsigned short* Pw = &Ps[w * 32 * LDP];

    // Q A-fragments (pre-scaled in QKV epilogue), held in regs whole kernel
    bf16x8 qf[2][2];
#pragma unroll
    for (int m = 0; m < 2; ++m)
#pragma unroll
        for (int h = 0; h < 2; ++h)
            qf[m][h] = *(const bf16x8*)(Q + qkbase + (size_t)(q0 + 16 * m + l15) * 64 + h * 32 + quad * 8);

    const f32x4 zero = {0.f, 0.f, 0.f, 0.f};
    f32x4 O[2][4], lac[2];
#pragma unroll
    for (int m = 0; m < 2; ++m) {
        lac[m] = zero;
#pragma unroll
        for (int dj = 0; dj < 4; ++dj) O[m][dj] = zero;
    }
    float mrow[2][4];
#pragma unroll
    for (int m = 0; m < 2; ++m)
#pragma unroll
        for (int r = 0; r < 4; ++r) mrow[m][r] = -INFINITY;

    const short ONE = (short)0x3F80;  // bf16 1.0
    const bf16x8 onesf = {ONE, ONE, ONE, ONE, ONE, ONE, ONE, ONE};

    const int nkt = qi / 2 + 1;       // key tiles 0..nkt-1 (causal)
    for (int kt = 0; kt < nkt; ++kt) {
        const int kbase = kt * 64;

        // ---- S = Q K^T : 2 row-blocks x 64 keys
        f32x4 s[2][4];
#pragma unroll
        for (int nj = 0; nj < 4; ++nj) {
            const unsigned short* kp = K + qkbase + (size_t)(kbase + nj * 16 + l15) * 64 + quad * 8;
            bf16x8 kf0 = *(const bf16x8*)kp;
            bf16x8 kf1 = *(const bf16x8*)(kp + 32);
#pragma unroll
            for (int m = 0; m < 2; ++m) {
                f32x4 z = __builtin_amdgcn_mfma_f32_16x16x32_bf16(qf[m][0], kf0, zero, 0, 0, 0);
                s[m][nj] = __builtin_amdgcn_mfma_f32_16x16x32_bf16(qf[m][1], kf1, z, 0, 0, 0);
            }
        }

        // ---- causal mask (diagonal tile only; wave-uniform branch)
        if (kt == nkt - 1) {
#pragma unroll
            for (int m = 0; m < 2; ++m)
#pragma unroll
                for (int nj = 0; nj < 4; ++nj)
#pragma unroll
                    for (int r = 0; r < 4; ++r)
                        if (kbase + nj * 16 + l15 > q0 + 16 * m + quad * 4 + r)
                            s[m][nj][r] = -INFINITY;
        }

        // ---- online softmax: row max (reduce over l15 via 4 xor-shuffles)
        f32x4 al[2];
#pragma unroll
        for (int m = 0; m < 2; ++m) {
#pragma unroll
            for (int r = 0; r < 4; ++r) {
                float v = fmaxf(fmaxf(s[m][0][r], s[m][1][r]), fmaxf(s[m][2][r], s[m][3][r]));
                v = fmaxf(v, __shfl_xor(v, 1));
                v = fmaxf(v, __shfl_xor(v, 2));
                v = fmaxf(v, __shfl_xor(v, 4));
                v = fmaxf(v, __shfl_xor(v, 8));
                float mnew = fmaxf(mrow[m][r], v);
                al[m][r] = exp2f(mrow[m][r] - mnew);
                mrow[m][r] = mnew;
            }
        }

        // ---- p = exp2(s - m), pack to LDS (wave-private)
#pragma unroll
        for (int m = 0; m < 2; ++m)
#pragma unroll
            for (int nj = 0; nj < 4; ++nj)
#pragma unroll
                for (int r = 0; r < 4; ++r)
                    Pw[(16 * m + quad * 4 + r) * LDP + nj * 16 + l15] =
                        f2bf(exp2f(s[m][nj][r] - mrow[m][r]));

        // ---- rescale running O and l by alpha
#pragma unroll
        for (int m = 0; m < 2; ++m) {
            lac[m] *= al[m];
#pragma unroll
            for (int dj = 0; dj < 4; ++dj) O[m][dj] *= al[m];
        }

        // ---- read P back as A-fragments (same-wave LDS RAW; no barrier)
        bf16x8 pa[2][2];
#pragma unroll
        for (int m = 0; m < 2; ++m) {
            pa[m][0] = *(const bf16x8*)&Pw[(16 * m + l15) * LDP + quad * 8];
            pa[m][1] = *(const bf16x8*)&Pw[(16 * m + l15) * LDP + 32 + quad * 8];
            // l += P @ ones (row-sum via matrix pipe, same alpha recurrence as O)
            f32x4 z = __builtin_amdgcn_mfma_f32_16x16x32_bf16(pa[m][0], onesf, lac[m], 0, 0, 0);
            lac[m] = __builtin_amdgcn_mfma_f32_16x16x32_bf16(pa[m][1], onesf, z, 0, 0, 0);
        }

        // ---- O += P V (V B-frags direct from global Vt, contiguous 16B/lane)
#pragma unroll
        for (int dj = 0; dj < 4; ++dj) {
            const unsigned short* vp = Vt + vbase + (size_t)(dj * 16 + l15) * 4096 + kbase + quad * 8;
            bf16x8 vf0 = *(const bf16x8*)vp;
            bf16x8 vf1 = *(const bf16x8*)(vp + 32);
#pragma unroll
            for (int m = 0; m < 2; ++m) {
                f32x4 z = __builtin_amdgcn_mfma_f32_16x16x32_bf16(pa[m][0], vf0, O[m][dj], 0, 0, 0);
                O[m][dj] = __builtin_amdgcn_mfma_f32_16x16x32_bf16(pa[m][1], vf1, z, 0, 0, 0);
            }
        }
    }

    // ---- epilogue: O / l -> Y [b][t][h*64+d] bf16
    const int b = bh / 12, h = bh % 12;
#pragma unroll
    for (int m = 0; m < 2; ++m)
#pragma unroll
        for (int r = 0; r < 4; ++r) {
            float inv = 1.0f / lac[m][r];
            int t = q0 + 16 * m + quad * 4 + r;
            size_t base = ((size_t)(b * 4096 + t)) * 768 + h * 64;
#pragma unroll
            for (int dj = 0; dj < 4; ++dj)
                Y[base + dj * 16 + l15] = f2bf(O[m][dj][r] * inv);
        }
}

// ---------------- launch ----------------
extern "C" void kernel_launch(void* const* d_in, const int* in_sizes, int n_in,
                              void* d_out, int out_size, void* d_ws, size_t ws_size,
                              hipStream_t stream) {
    (void)in_sizes; (void)n_in; (void)out_size; (void)ws_size;
    const float* x     = (const float*)d_in[0];
    const float* Wqkv  = (const float*)d_in[1];
    const float* bqkv  = (const float*)d_in[2];
    const float* Wproj = (const float*)d_in[3];
    const float* bproj = (const float*)d_in[4];
    float* out = (float*)d_out;

    char* ws = (char*)d_ws;
    size_t off = 0;
    auto alloc = [&](size_t bytes) -> void* {
        void* p = ws + off;
        off += (bytes + 255) & ~(size_t)255;
        return p;
    };
    unsigned short* xb     = (unsigned short*)alloc((size_t)8192 * 768 * 2);
    unsigned short* WqkvT  = (unsigned short*)alloc((size_t)2304 * 768 * 2);
    unsigned short* WprojT = (unsigned short*)alloc((size_t)768 * 768 * 2);
    unsigned short* Qb     = (unsigned short*)alloc((size_t)24 * 4096 * 64 * 2);
    unsigned short* Kb     = (unsigned short*)alloc((size_t)24 * 4096 * 64 * 2);
    unsigned short* Vtb    = (unsigned short*)alloc((size_t)24 * 64 * 4096 * 2);
    unsigned short* Yb     = (unsigned short*)alloc((size_t)8192 * 768 * 2);

    k_convert<<<6144, 256, 0, stream>>>(x, xb, 8192 * 768 / 4);
    dim3 tb(32, 8);
    k_transpose<<<dim3(72, 24), tb, 0, stream>>>(Wqkv, WqkvT, 768, 2304);
    k_transpose<<<dim3(24, 24), tb, 0, stream>>>(Wproj, WprojT, 768, 768);
    k_gemm_qkv<<<dim3(64, 18), 256, 0, stream>>>(xb, WqkvT, bqkv, Qb, Kb, Vtb);
    k_attn<<<dim3(32, 24), 256, 0, stream>>>(Qb, Kb, Vtb, Yb);
    k_gemm_proj<<<dim3(64, 6), 256, 0, stream>>>(Yb, WprojT, bproj, out);
}